// Round 11
// baseline (76.584 us; speedup 1.0000x reference)
//
#include <hip/hip_runtime.h>

#define NJ 8
#define TS 2048
#define NB 1024
#define JW 4                    // joints per half-block
#define CHUNK 128               // 64 lanes * 2 steps per wave-scan
#define NCH (TS / CHUNK)        // 16
#define F4C (CHUNK * JW)        // 512 float4 = 8 KB per buffer
#define DTC (1.0f / 60.0f)

// async global->LDS, 16B per lane. lds_base must be wave-uniform; HW writes
// lds_base + lane*16. Global src is per-lane.
__device__ __forceinline__ void dma16(const float4* g, float4* lds_base) {
#if __has_builtin(__builtin_amdgcn_global_load_lds)
    __builtin_amdgcn_global_load_lds(
        (const __attribute__((address_space(1))) void*)g,
        (__attribute__((address_space(3))) void*)lds_base,
        16, 0, 0);
#else
    lds_base[threadIdx.x & 63] = *g;
#endif
}

// DPP cross-lane move, all-VALU (no DS pipe). CTRL: row_shr:N = 0x110+N,
// row_bcast15 = 0x142, row_bcast31 = 0x143.
template<int CTRL>
__device__ __forceinline__ float dppf(float v) {
    return __int_as_float(__builtin_amdgcn_update_dpp(
        __float_as_int(v), __float_as_int(v), CTRL, 0xF, 0xF, false));
}

#define ROUND(CTRL, COND) do {                                          \
    float o_r0 = dppf<CTRL>(r0), o_r1 = dppf<CTRL>(r1),                 \
          o_rc = dppf<CTRL>(rc), o_s0 = dppf<CTRL>(s0),                 \
          o_s1 = dppf<CTRL>(s1), o_sc = dppf<CTRL>(sc);                 \
    if (COND) {                                                         \
        float nr0 = fmaf(r0, o_s0, r1 * o_r0);                          \
        float nr1 = fmaf(r0, o_s1, r1 * o_r1);                          \
        float nrc = fmaf(r0, o_sc, fmaf(r1, o_rc, rc));                 \
        float ns0 = fmaf(s0, o_s0, s1 * o_r0);                          \
        float ns1 = fmaf(s0, o_s1, s1 * o_r1);                          \
        float nsc = fmaf(s0, o_sc, fmaf(s1, o_rc, sc));                 \
        r0 = nr0; r1 = nr1; rc = nrc; s0 = ns0; s1 = ns1; sc = nsc;     \
    } } while (0)

__global__ __launch_bounds__(256, 8) void phys_dpp128_kernel(
    const float4* __restrict__ x,       // (B,T,8) as float4 per (t,joint)
    const float*  __restrict__ state0,  // (B,8,2)
    const float*  __restrict__ M,       // (8,2)
    const float*  __restrict__ inertia, // (8,)
    const float*  __restrict__ damping, // (8,)
    float* __restrict__ out,            // (B,T,8)
    float* __restrict__ muscle,         // (B,8,2,2)
    float* __restrict__ finals)         // (B,8,2)
{
    __shared__ float4 xin[2][F4C];           // 2 x 8 KB input double-buffer
    __shared__ float4 tb[2][CHUNK * JW / 4]; // 2 x 2 KB theta transpose dbuf

    // sibling half-blocks (same batch) differ by 8 in blockIdx -> same XCD,
    // dispatched back-to-back -> partial output lines merge in shared L2.
    const int g   = blockIdx.x;
    const int b   = (g & 7) | ((g >> 4) << 3);
    const int J0  = ((g >> 3) & 1) * JW;

    const int tid  = threadIdx.x;
    const int w    = tid >> 6;          // wave id = joint offset in half
    const int lane = tid & 63;
    const int j    = J0 + w;

    const float M0  = M[j * 2 + 0];
    const float M1  = M[j * 2 + 1];
    const float M20 = M0 * M0;
    const float M21 = M1 * M1;
    const float d   = damping[j];
    const float p   = DTC / inertia[j];      // DT / I
    const float gd  = 1.0f - p * d;          // dθ self-coefficient

    float thc  = state0[(b * NJ + j) * 2 + 0];
    float dthc = state0[(b * NJ + j) * 2 + 1];

    const float4* xb = x + (size_t)b * TS * NJ;

    // xin layout: natural n = 4*t_local + jl (n 0..511); stored at
    // sigma(n) = n ^ ((n>>3)&7) (involution: bits 3-5 XOR'd into 0-2).
    // DMA dest linear dd = 128w + 64i + lane; global element n = sigma(dd).
    // Each dma16 covers 16 full 64-B half-rows (dense).
    auto issue = [&](int ch, float4* bb) {
        const int T0 = ch * CHUNK;
        #pragma unroll
        for (int i = 0; i < 2; ++i) {
            int dd = 128 * w + 64 * i + lane;
            int n  = dd ^ ((dd >> 3) & 7);
            const float4* src = xb + (size_t)(T0 + (n >> 2)) * NJ + J0 + (n & 3);
            dma16(src, bb + 128 * w + 64 * i);
        }
    };

    // prologue: async-stage chunk 0
    issue(0, xin[0]);

    for (int ch = 0; ch <= NCH; ++ch) {
        // single barrier per chunk: drains DMA(ch) [vmcnt] and makes
        // tout(ch-1) visible [lgkmcnt]; also buffer-overwrite safety.
        __syncthreads();

        // issue DMA for chunk ch+1 into the other xin buffer (full-chunk slack)
        if (ch + 1 < NCH) issue(ch + 1, xin[(ch + 1) & 1]);

        // ---- store phase: coalesced write-out of chunk ch-1's theta ----
        // tout word wd stored at wd ^ ((wd>>5)&15). Thread f<128 handles
        // t=f: words 4f+c; m=(f>>3)&15 const over c; b128 block q=f^((f>>5)&3),
        // components permuted by pm=m&3=(f>>3)&3.
        if (ch > 0 && tid < 128) {
            const float4* tr = tb[(ch - 1) & 1];
            int f  = tid;
            int q  = f ^ ((f >> 5) & 3);
            int pm = (f >> 3) & 3;
            float4 r = tr[q];
            float rx = r.x, ry = r.y, rz = r.z, rw = r.w;
            if (pm & 1) { float tq = rx; rx = ry; ry = tq; tq = rz; rz = rw; rw = tq; }
            if (pm & 2) { float tq = rx; rx = rz; rz = tq; tq = ry; ry = rw; rw = tq; }
            float4* og = (float4*)out
                       + 2 * ((size_t)b * TS + (size_t)(ch - 1) * CHUNK + f)
                       + (J0 >> 2);
            *og = make_float4(rx, ry, rz, rw);
        }

        if (ch < NCH) {
            // ---- compute phase on xin[ch&1] ----
            const float4* xc = xin[ch & 1];
            float* tw = (float*)tb[ch & 1];

            // element (step 2*lane+k, joint w): natural n = 8*lane + 4k + w,
            // read at n ^ ((n>>3)&7) = n ^ (lane&7)  -> 8 lanes/bank-group
            float a[2], cc[2];
            const int bm = lane & 7;
            #pragma unroll
            for (int k = 0; k < 2; ++k) {
                int n = 8 * lane + 4 * k + w;
                float4 v = xc[n ^ bm];
                a[k]  = fmaf(M0,  v.x, M1  * v.y);   // einsum(M, F_t)
                cc[k] = fmaf(M20, v.z, M21 * v.w);   // einsum(M2, K_t)
            }

            // serially compose my 2 step-maps:
            //   dθ' = r0·θ + r1·dθ + rc ;  θ' = s0·θ + s1·dθ + sc
            float r0 = 0.0f, r1 = 1.0f, rc = 0.0f;   // identity
            float s0 = 1.0f, s1 = 0.0f, sc = 0.0f;
            #pragma unroll
            for (int k = 0; k < 2; ++k) {
                float pa = p * a[k];
                float pc = p * cc[k];
                float nr0 = fmaf(-pc, s0, gd * r0);
                float nr1 = fmaf(-pc, s1, gd * r1);
                float nrc = fmaf(-pc, sc, fmaf(gd, rc, pa));
                s0 = fmaf(DTC, nr0, s0);
                s1 = fmaf(DTC, nr1, s1);
                sc = fmaf(DTC, nrc, sc);
                r0 = nr0; r1 = nr1; rc = nrc;
            }

            // inclusive scan over 64 lanes — DPP wave-scan, all VALU
            ROUND(0x111, (lane & 15) >= 1);
            ROUND(0x112, (lane & 15) >= 2);
            ROUND(0x114, (lane & 15) >= 4);
            ROUND(0x118, (lane & 15) >= 8);
            ROUND(0x142, (lane & 31) >= 16);
            ROUND(0x143, lane >= 32);

            // end state after my steps = inclusive map applied to carry;
            // my start state = lane (l-1)'s end state, shifted up by 1.
            float th_e  = fmaf(s0, thc, fmaf(s1, dthc, sc));
            float dth_e = fmaf(r0, thc, fmaf(r1, dthc, rc));
            float th  = __shfl_up(th_e, 1, 64);
            float dth = __shfl_up(dth_e, 1, 64);
            if (lane == 0) { th = thc; dth = dthc; }

            // replay 2 steps in exact reference op-order; θ -> transpose buf.
            // word wd = 8*lane + 4k + w; store at wd ^ ((wd>>5)&15)
            //         = wd ^ ((lane>>2)&15)   (2 lanes/bank = free)
            const int wsig = (lane >> 2) & 15;
            #pragma unroll
            for (int k = 0; k < 2; ++k) {
                float u = fmaf(-cc[k], th, a[k]);    // a - c·θ
                u = fmaf(-d, dth, u);                // ... - d·dθ
                dth = fmaf(p, u, dth);
                th  = fmaf(DTC, dth, th);
                tw[(8 * lane + 4 * k + w) ^ wsig] = th;
            }

            // carry = lane 63's end state (uniform lane -> v_readlane)
            thc  = __shfl(th, 63, 64);
            dthc = __shfl(dth, 63, 64);
        }
    }

    if (lane == 0) {
        const int idx = b * NJ + j;
        finals[idx * 2 + 0] = thc;
        finals[idx * 2 + 1] = dthc;
        muscle[idx * 4 + 0] = thc  * M0;
        muscle[idx * 4 + 1] = thc  * M1;
        muscle[idx * 4 + 2] = dthc * M0;
        muscle[idx * 4 + 3] = dthc * M1;
    }
}

extern "C" void kernel_launch(void* const* d_in, const int* in_sizes, int n_in,
                              void* d_out, int out_size, void* d_ws, size_t ws_size,
                              hipStream_t stream) {
    const float4* x      = (const float4*)d_in[0];
    const float*  state0 = (const float*)d_in[1];
    const float*  M      = (const float*)d_in[2];
    const float*  inertia= (const float*)d_in[3];
    const float*  damping= (const float*)d_in[4];

    float* out    = (float*)d_out;                       // (B,T,8)
    float* muscle = out + (size_t)NB * TS * NJ;          // (B,8,2,2)
    float* finals = muscle + (size_t)NB * NJ * 2 * 2;    // (B,8,2)

    dim3 block(256);          // 4 waves = 4 joints (half batch)
    dim3 grid(NB * 2);        // 2048 half-blocks; siblings 8 apart (same XCD)
    phys_dpp128_kernel<<<grid, block, 0, stream>>>(x, state0, M, inertia, damping,
                                                   out, muscle, finals);
}